// Round 15
// baseline (374.369 us; speedup 1.0000x reference)
//
#include <hip/hip_runtime.h>

static constexpr int T_LEN = 1024;

typedef _Float16 f16;
typedef f16  f16x4 __attribute__((ext_vector_type(4)));
typedef float f32x4 __attribute__((ext_vector_type(4)));

__device__ __forceinline__ f32x4 mfma16(f16x4 a, f16x4 b, f32x4 c) {
    return __builtin_amdgcn_mfma_f32_16x16x16f16(a, b, c, 0, 0, 0);
}
// 1/(1+2^t): overflow-safe (t->+inf: exp2=inf, rcp->0; t->-inf: ->1)
__device__ __forceinline__ float sig2(float t) {
    return __builtin_amdgcn_rcpf(1.f + __builtin_amdgcn_exp2f(t));
}

// Round-15: PRODUCER/CONSUMER LAYER SPLIT. 2 waves (128 thr) per block,
// 16 seqs per block, 256 blocks = 1 block/CU (2 active SIMDs, each with a
// fully self-sufficient wave).
//
// Wave 0 = layer 1, solo (round-6-verified structure): per gate-group g,
// D = mfma(Whh0[g], h1f, Wih0[g]*x+b) gives lane (n,Lq) the gate g of units
// 4Lq..4Lq+3 for seq n; after the elementwise update, h1f (units 4Lq+r) is
// exactly the next step's B-fragment (D==B lane mapping) -> ZERO cross-lane,
// ZERO barrier in the recurrence. Publishes h1[t] to ring[t&7] (b64).
//
// Wave 1 = layer 2, solo, FOUR steps behind: reads h1[s] from the ring
// (guaranteed published before the last barrier), gb = mfma(Wih1[g], h1x,
// pre2[g]) with pre2 = mfma(Whh1[g], h2f, b2) refreshed post-update
// (round-7 pipeline). Barrier cadence: ONE per 4 steps. Ring parity: in
// window kk, wave0 writes slots {0..3} (kk even) / {4..7} (kk odd); wave1
// reads the opposite half -> disjoint; the window barrier orders handoff.
__global__ void __launch_bounds__(128, 1) lstm2_pc_kernel(
    const float* __restrict__ x,
    const float* __restrict__ Wih0, const float* __restrict__ Whh0,
    const float* __restrict__ bih0, const float* __restrict__ bhh0,
    const float* __restrict__ Wih1, const float* __restrict__ Whh1,
    const float* __restrict__ bih1, const float* __restrict__ bhh1,
    const float* __restrict__ Wout, const float* __restrict__ bout,
    float* __restrict__ out)
{
    const int tid = threadIdx.x;
    const int w   = tid >> 6;          // 0 = L1 producer, 1 = L2 consumer
    const int l   = tid & 63;
    const int n   = l & 15;            // seq col (A row / B-D col)
    const int Lq  = l >> 4;            // lane quad -> units 4Lq..4Lq+3
    const int seq = blockIdx.x * 16 + n;

    // x tile, f16 (dword stride 514 -> conflict-free; L1 reads are per-row
    // broadcasts anyway).
    __shared__ __align__(16) f16 x_lds[16][1028];
    // h1 ring: [slot][seq][16 units + 2 pad] -> 36B row stride; b64 access
    // banks (9n+2Lq)%32, max 2-way (free).
    __shared__ __align__(16) f16 ring[8][16][18];

    // ---- stage x (f32 global -> f16 LDS), coalesced, once.
    {
        const float* xblk = x + (size_t)blockIdx.x * 16 * T_LEN;
#pragma unroll 4
        for (int jj = 0; jj < 32; ++jj) {
            const int flat = jj * 512 + tid * 4;       // f32 quad index
            const int row  = flat >> 10, col = flat & 1023;
            const float4 v = *reinterpret_cast<const float4*>(
                xblk + (size_t)row * T_LEN + col);
            f16x4 h4; h4[0] = (f16)v.x; h4[1] = (f16)v.y;
                      h4[2] = (f16)v.z; h4[3] = (f16)v.w;
            *reinterpret_cast<f16x4*>(&x_lds[row][col]) = h4;
        }
    }

    const float L2E = 1.442695041f;
    const float NT  = -2.f * L2E;      // tanh(c) scale

    // ---- per-wave constant fragments (f16 weights pre-scaled by -log2e;
    //      tanh group g==2 by -2log2e). A: row = n, k = 4Lq+r.
    //      D-side constants: row = g*16 + 4Lq + r.
    f16x4 WA[4] = {}, WB[4] = {};
    f32x4 cbD[4], wxD[4] = {};
#pragma unroll
    for (int g = 0; g < 4; ++g) {
        const float ns   = (g == 2) ? (-2.f * L2E) : (-L2E);
        const int   arow = g * 16 + n;
#pragma unroll
        for (int r = 0; r < 4; ++r) {
            const int drow = g * 16 + 4 * Lq + r;
            if (w == 0) {
                WA[g][r]  = (f16)(ns * Whh0[arow * 16 + 4 * Lq + r]);
                cbD[g][r] = ns * (bih0[drow] + bhh0[drow]);
                wxD[g][r] = ns * Wih0[drow];
            } else {
                WA[g][r]  = (f16)(ns * Wih1[arow * 16 + 4 * Lq + r]);
                WB[g][r]  = (f16)(ns * Whh1[arow * 16 + 4 * Lq + r]);
                cbD[g][r] = ns * (bih1[drow] + bhh1[drow]);
            }
        }
    }
#pragma unroll
    for (int g = 0; g < 4; ++g)
        asm volatile("" : "+v"(WA[g]), "+v"(WB[g]), "+v"(cbD[g]), "+v"(wxD[g]));

    f16x4 h1f = {}, h2f = {};          // own-layer h fragments (B layout)
    f32x4 cc  = {0.f, 0.f, 0.f, 0.f}; // c1 (w0) / c2 (w1), units 4Lq+r
    f32x4 h2v = {0.f, 0.f, 0.f, 0.f};
    f32x4 pre2[4];                     // w1: Whh1·h2 + b2 (h2[-1]=0)
#pragma unroll
    for (int g = 0; g < 4; ++g) pre2[g] = cbD[g];

    __syncthreads();                   // x staged

    for (int kk = 0; kk < 256; ++kk) {
        if (w == 0) {
            // ---- L1: steps t = 4kk .. 4kk+3 (register-chain only)
            const f16x4 xq = *reinterpret_cast<const f16x4*>(&x_lds[n][4 * kk]);
#pragma unroll
            for (int u = 0; u < 4; ++u) {
                const float xv = (float)xq[u];
                f32x4 s4[4];
#pragma unroll
                for (int g = 0; g < 4; ++g) {
                    f32x4 ci;
#pragma unroll
                    for (int r = 0; r < 4; ++r)
                        ci[r] = fmaf(wxD[g][r], xv, cbD[g][r]);
                    const f32x4 d = mfma16(WA[g], h1f, ci);
#pragma unroll
                    for (int r = 0; r < 4; ++r) s4[g][r] = sig2(d[r]);
                }
#pragma unroll
                for (int r = 0; r < 4; ++r) {
                    const float gg = fmaf(2.f, s4[2][r], -1.f);
                    cc[r] = fmaf(s4[1][r], cc[r], s4[0][r] * gg);
                    const float th = fmaf(2.f, sig2(NT * cc[r]), -1.f);
                    h1f[r] = (f16)(s4[3][r] * th);
                }
                *reinterpret_cast<f16x4*>(&ring[(4 * kk + u) & 7][n][4 * Lq]) = h1f;
            }
        } else if (kk > 0) {
            // ---- L2: steps s = 4(kk-1) .. 4(kk-1)+3 (ring slots ready)
            const int sb = 4 * (kk - 1);
#pragma unroll
            for (int u = 0; u < 4; ++u) {
                const int s = sb + u;
                const f16x4 h1x =
                    *reinterpret_cast<const f16x4*>(&ring[s & 7][n][4 * Lq]);
                f32x4 s4[4];
#pragma unroll
                for (int g = 0; g < 4; ++g) {
                    const f32x4 d = mfma16(WA[g], h1x, pre2[g]);
#pragma unroll
                    for (int r = 0; r < 4; ++r) s4[g][r] = sig2(d[r]);
                }
#pragma unroll
                for (int r = 0; r < 4; ++r) {
                    const float gg = fmaf(2.f, s4[2][r], -1.f);
                    cc[r] = fmaf(s4[1][r], cc[r], s4[0][r] * gg);
                    const float th = fmaf(2.f, sig2(NT * cc[r]), -1.f);
                    h2v[r] = s4[3][r] * th;
                    h2f[r] = (f16)h2v[r];
                }
#pragma unroll
                for (int g = 0; g < 4; ++g)
                    pre2[g] = mfma16(WB[g], h2f, cbD[g]);
            }
        }
        __syncthreads();               // window handoff (1 per 4 steps)
    }

    // ---- tail: L2 steps s = 1020..1023 (slots 4..7, written in kk=255,
    //      ordered by its trailing barrier) + head.
    if (w == 1) {
#pragma unroll
        for (int u = 0; u < 4; ++u) {
            const int s = 1020 + u;
            const f16x4 h1x =
                *reinterpret_cast<const f16x4*>(&ring[s & 7][n][4 * Lq]);
            f32x4 s4[4];
#pragma unroll
            for (int g = 0; g < 4; ++g) {
                const f32x4 d = mfma16(WA[g], h1x, pre2[g]);
#pragma unroll
                for (int r = 0; r < 4; ++r) s4[g][r] = sig2(d[r]);
            }
#pragma unroll
            for (int r = 0; r < 4; ++r) {
                const float gg = fmaf(2.f, s4[2][r], -1.f);
                cc[r] = fmaf(s4[1][r], cc[r], s4[0][r] * gg);
                const float th = fmaf(2.f, sig2(NT * cc[r]), -1.f);
                h2v[r] = s4[3][r] * th;
                h2f[r] = (f16)h2v[r];
            }
#pragma unroll
            for (int g = 0; g < 4; ++g)
                pre2[g] = mfma16(WB[g], h2f, cbD[g]);
        }

        // ---- head: out[seq][m] = relu(h2) . Wout[m] + bout[m]
        // lane holds h2 of units 4Lq+r for seq n; reduce over Lq.
#pragma unroll
        for (int m5 = 0; m5 < 5; ++m5) {
            float p = 0.f;
#pragma unroll
            for (int r = 0; r < 4; ++r)
                p = fmaf(fmaxf(h2v[r], 0.f), Wout[m5 * 16 + 4 * Lq + r], p);
            p += __shfl_xor(p, 16, 64);
            p += __shfl_xor(p, 32, 64);
            if (Lq == 0) out[seq * 5 + m5] = p + bout[m5];
        }
    }
}

extern "C" void kernel_launch(void* const* d_in, const int* in_sizes, int n_in,
                              void* d_out, int out_size, void* d_ws, size_t ws_size,
                              hipStream_t stream) {
    const float* x    = (const float*)d_in[0];
    const float* Wih0 = (const float*)d_in[1];
    const float* Whh0 = (const float*)d_in[2];
    const float* bih0 = (const float*)d_in[3];
    const float* bhh0 = (const float*)d_in[4];
    const float* Wih1 = (const float*)d_in[5];
    const float* Whh1 = (const float*)d_in[6];
    const float* bih1 = (const float*)d_in[7];
    const float* bhh1 = (const float*)d_in[8];
    const float* Wout = (const float*)d_in[9];
    const float* bout = (const float*)d_in[10];
    float* out = (float*)d_out;

    const int B = in_sizes[0] / T_LEN;          // 4096
    dim3 grid(B / 16), block(128);              // 2 waves / 16 seqs per block
    hipLaunchKernelGGL(lstm2_pc_kernel, grid, block, 0, stream,
                       x, Wih0, Whh0, bih0, bhh0,
                       Wih1, Whh1, bih1, bhh1, Wout, bout, out);
}

// Round 16
// 274.430 us; speedup vs baseline: 1.3642x; 1.3642x over previous
//
#include <hip/hip_runtime.h>

static constexpr int T_LEN = 1024;

typedef _Float16 f16;
typedef f16  f16x4 __attribute__((ext_vector_type(4)));
typedef float f32x4 __attribute__((ext_vector_type(4)));

__device__ __forceinline__ f32x4 mfma16(f16x4 a, f16x4 b, f32x4 c) {
    return __builtin_amdgcn_mfma_f32_16x16x16f16(a, b, c, 0, 0, 0);
}
// 1/(1+2^t): overflow-safe (t->+inf: exp2=inf, rcp->0; t->-inf: ->1)
__device__ __forceinline__ float sig2(float t) {
    return __builtin_amdgcn_rcpf(1.f + __builtin_amdgcn_exp2f(t));
}

// Round-16: FUSED DUAL-ROLE WAVES. 4 waves (256 thr) per block, 16 seqs,
// 256 blocks = 1 wave/SIMD. Wave q owns unit-block q for BOTH layers
// (round-12's waves (0,q) and (1,q) merged). ROW-INTERLEAVED A-fragments
// (round-10-verified) keep the LSTM update lane-local: lane (n,Lq) owns
// unit u1 = 4q+Lq of seq n.
//
// Pipeline (the point of the fusion): L2 runs TWO steps behind, with all
// its inputs register-carried:
//   iter t:  [L2 step t-2: pre2n = mfma(WB, rh2=h2[t-3], cb2);
//             d2 = mfma(WAx, h1A=h1[t-2], pre2n); sig; update; write h2]
//            [L1 step t:  d1 = mfma(WA, rh1=h1[t-1](reg!), ci); sig;
//             update; write h1]
//            barrier
//            [issue reads: rh1=h1[t], rh2=h2[t-2] — consumed NEXT iter]
// The two compute chains are independent (mutual latency hiding in one
// wave); no ds_read sits on the critical path (reads have a full iter of
// slack); barrier domain is only 4 waves. Arithmetic identical to R12.
__global__ void __launch_bounds__(256, 1) lstm2_fw_kernel(
    const float* __restrict__ x,
    const float* __restrict__ Wih0, const float* __restrict__ Whh0,
    const float* __restrict__ bih0, const float* __restrict__ bhh0,
    const float* __restrict__ Wih1, const float* __restrict__ Whh1,
    const float* __restrict__ bih1, const float* __restrict__ bhh1,
    const float* __restrict__ Wout, const float* __restrict__ bout,
    float* __restrict__ out)
{
    const int tid = threadIdx.x;
    const int q   = tid >> 6;          // fused wave: unit-block q, both layers
    const int l   = tid & 63;
    const int n   = l & 15;            // seq col (B/D); A tile-row
    const int Lq  = l >> 4;            // lane quad
    const int seq = blockIdx.x * 16 + n;

    // x tile, f16 (dword stride 514 -> conflict-free b64 reads).
    __shared__ __align__(16) f16   x_lds[16][1028];
    // h exchange: [slot][layer][seq][16 units + 4 pad].
    __shared__ __align__(16) f16   hx[2][2][16][20];
    __shared__ __align__(16) float h2fin[16][20];

    // ---- stage x (f32 global -> f16 LDS), coalesced, once.
    {
        const float* xblk = x + (size_t)blockIdx.x * 16 * T_LEN;
#pragma unroll 4
        for (int jj = 0; jj < 16; ++jj) {
            const int flat = jj * 1024 + tid * 4;      // f32 quad index
            const int row  = flat >> 10, col = flat & 1023;
            const float4 v = *reinterpret_cast<const float4*>(
                xblk + (size_t)row * T_LEN + col);
            f16x4 h4; h4[0] = (f16)v.x; h4[1] = (f16)v.y;
                      h4[2] = (f16)v.z; h4[3] = (f16)v.w;
            *reinterpret_cast<f16x4*>(&x_lds[row][col]) = h4;
        }
    }

    const float L2E = 1.442695041f;
    const float NT  = -2.f * L2E;      // tanh(c) scale

    // A rows (tile-row m = lane&15): gate m&3, unit 4q + (m>>2).
    const int   gA    = n & 3;
    const int   wrowA = gA * 16 + 4 * q + (n >> 2);
    const float nsA   = (gA == 2) ? (-2.f * L2E) : (-L2E);
    // D rows (reg r): gate r, unit u1 = 4q + Lq.
    const int   u1    = 4 * q + Lq;

    f16x4 WA, WAx, WB;                 // A-frags: Whh0, Wih1, Whh1
    f32x4 cb1, wx0, cb2;               // D-layout: bias1, Wih0, bias2
#pragma unroll
    for (int r = 0; r < 4; ++r) {
        const float nsD  = (r == 2) ? (-2.f * L2E) : (-L2E);
        const int   wrdD = r * 16 + u1;
        WA[r]  = (f16)(nsA * Whh0[wrowA * 16 + 4 * Lq + r]);
        WAx[r] = (f16)(nsA * Wih1[wrowA * 16 + 4 * Lq + r]);
        WB[r]  = (f16)(nsA * Whh1[wrowA * 16 + 4 * Lq + r]);
        cb1[r] = nsD * (bih0[wrdD] + bhh0[wrdD]);
        wx0[r] = nsD * Wih0[wrdD];
        cb2[r] = nsD * (bih1[wrdD] + bhh1[wrdD]);
    }
    asm volatile("" : "+v"(WA), "+v"(WAx), "+v"(WB),
                      "+v"(cb1), "+v"(wx0), "+v"(cb2));

    // register-carried pipeline state
    f16x4 rh1 = {};                    // h1[t-1] fragment (read iter t-1)
    f16x4 h1A = {};                    // h1[t-2] fragment
    f16x4 rh2 = {};                    // h2[t-3] fragment (read iter t-1)
    f32x4 pre2;                        // scratch
    float c1 = 0.f, c2 = 0.f;
    f32x4 h2w = {0.f, 0.f, 0.f, 0.f}; // unused lanes placate compiler

    __syncthreads();                   // x staged; orders weight loads

    f16x4 xq = *reinterpret_cast<const f16x4*>(&x_lds[n][0]);

    for (int tb = 0; tb < T_LEN; tb += 4) {
        f16x4 xn = xq;
        if (tb + 4 < T_LEN)
            xn = *reinterpret_cast<const f16x4*>(&x_lds[n][tb + 4]);
#pragma unroll
        for (int u = 0; u < 4; ++u) {
            const int t    = tb + u;
            const int slot = u & 1;            // == t&1

            // ---- L2 step t-2: all-register inputs (uniform guard).
            if (t >= 2) {
                const f32x4 p2 = mfma16(WB, rh2, cb2);  // Whh1·h2[t-3]+b2
                const f32x4 d2 = mfma16(WAx, h1A, p2);  // +Wih1·h1[t-2]
                const float si = sig2(d2[0]);
                const float sf = sig2(d2[1]);
                const float sg = fmaf(2.f, sig2(d2[2]), -1.f);
                const float so = sig2(d2[3]);
                c2 = fmaf(sf, c2, si * sg);
                const float th = fmaf(2.f, sig2(NT * c2), -1.f);
                hx[slot][1][n][u1] = (f16)(so * th);    // h2[t-2]
            }

            // ---- L1 step t: rh1 = h1[t-1] already in registers.
            {
                const float xv = (float)xq[u];
                f32x4 ci;
#pragma unroll
                for (int r = 0; r < 4; ++r)
                    ci[r] = fmaf(wx0[r], xv, cb1[r]);
                const f32x4 d1 = mfma16(WA, rh1, ci);
                const float si = sig2(d1[0]);
                const float sf = sig2(d1[1]);
                const float sg = fmaf(2.f, sig2(d1[2]), -1.f);
                const float so = sig2(d1[3]);
                c1 = fmaf(sf, c1, si * sg);
                const float th = fmaf(2.f, sig2(NT * c1), -1.f);
                hx[slot][0][n][u1] = (f16)(so * th);    // h1[t]
            }
            __syncthreads();

            // ---- post-barrier reads, consumed NEXT iter (full-iter slack)
            h1A = rh1;
            rh1 = *reinterpret_cast<const f16x4*>(&hx[slot][0][n][4 * Lq]);
            if (t >= 2)
                rh2 = *reinterpret_cast<const f16x4*>(&hx[slot][1][n][4 * Lq]);
        }
        xq = xn;
    }

    // ---- epilogue: L2 steps T-2 and T-1.
    // Regs: rh1 = h1[T-1], h1A = h1[T-2], rh2 = h2[T-3]... one more lag:
    // after iter T-1 (t=1023), L2 completed step 1021; rh2 = h2[1021].
    float h2fv;
    {
        // step 1022: needs h1[1022] = h1A, h2[1021] = rh2.
        const f32x4 p2 = mfma16(WB, rh2, cb2);
        const f32x4 d2 = mfma16(WAx, h1A, p2);
        const float si = sig2(d2[0]);
        const float sf = sig2(d2[1]);
        const float sg = fmaf(2.f, sig2(d2[2]), -1.f);
        const float so = sig2(d2[3]);
        c2 = fmaf(sf, c2, si * sg);
        const float th = fmaf(2.f, sig2(NT * c2), -1.f);
        hx[0][1][n][u1] = (f16)(so * th);               // h2[1022]
    }
    __syncthreads();
    {
        // step 1023: needs h1[1023] = rh1, h2[1022] from LDS.
        const f16x4 h2x = *reinterpret_cast<const f16x4*>(&hx[0][1][n][4 * Lq]);
        const f32x4 p2 = mfma16(WB, h2x, cb2);
        const f32x4 d2 = mfma16(WAx, rh1, p2);
        const float si = sig2(d2[0]);
        const float sf = sig2(d2[1]);
        const float sg = fmaf(2.f, sig2(d2[2]), -1.f);
        const float so = sig2(d2[3]);
        c2 = fmaf(sf, c2, si * sg);
        const float th = fmaf(2.f, sig2(NT * c2), -1.f);
        h2fv = so * th;
        h2fin[n][u1] = h2fv;                            // f32 for the head
    }
    __syncthreads();

    // ---- head (wave 0): out[seq][m] = relu(h2) . Wout[m] + bout[m]
    if (q == 0) {
        const f32x4 hv = *reinterpret_cast<const f32x4*>(&h2fin[n][4 * Lq]);
#pragma unroll
        for (int m5 = 0; m5 < 5; ++m5) {
            float p = 0.f;
#pragma unroll
            for (int r = 0; r < 4; ++r)
                p = fmaf(fmaxf(hv[r], 0.f), Wout[m5 * 16 + 4 * Lq + r], p);
            p += __shfl_xor(p, 16, 64);
            p += __shfl_xor(p, 32, 64);
            if (Lq == 0) out[seq * 5 + m5] = p + bout[m5];
        }
    }
}

extern "C" void kernel_launch(void* const* d_in, const int* in_sizes, int n_in,
                              void* d_out, int out_size, void* d_ws, size_t ws_size,
                              hipStream_t stream) {
    const float* x    = (const float*)d_in[0];
    const float* Wih0 = (const float*)d_in[1];
    const float* Whh0 = (const float*)d_in[2];
    const float* bih0 = (const float*)d_in[3];
    const float* bhh0 = (const float*)d_in[4];
    const float* Wih1 = (const float*)d_in[5];
    const float* Whh1 = (const float*)d_in[6];
    const float* bih1 = (const float*)d_in[7];
    const float* bhh1 = (const float*)d_in[8];
    const float* Wout = (const float*)d_in[9];
    const float* bout = (const float*)d_in[10];
    float* out = (float*)d_out;

    const int B = in_sizes[0] / T_LEN;          // 4096
    dim3 grid(B / 16), block(256);              // 4 fused waves / 16 seqs
    hipLaunchKernelGGL(lstm2_fw_kernel, grid, block, 0, stream,
                       x, Wih0, Whh0, bih0, bhh0,
                       Wih1, Whh1, bih1, bhh1, Wout, bout, out);
}

// Round 17
// 243.272 us; speedup vs baseline: 1.5389x; 1.1281x over previous
//
#include <hip/hip_runtime.h>

static constexpr int T_LEN = 1024;

typedef _Float16 f16;
typedef f16  f16x4 __attribute__((ext_vector_type(4)));
typedef f16  f16x8 __attribute__((ext_vector_type(8)));
typedef float f32x4 __attribute__((ext_vector_type(4)));

__device__ __forceinline__ f32x4 mfma_k32(f16x8 a, f16x8 b, f32x4 c) {
    return __builtin_amdgcn_mfma_f32_16x16x32_f16(a, b, c, 0, 0, 0);
}
// 1/(1+2^t): overflow-safe (t->+inf: exp2=inf, rcp->0; t->-inf: ->1)
__device__ __forceinline__ float sig2(float t) {
    return __builtin_amdgcn_rcpf(1.f + __builtin_amdgcn_exp2f(t));
}

// Round-17: ONE MFMA PER WAVE-STEP via K=32 packing + dual-layer row split.
// 8 waves (512 thr), 16 seqs, 256 blocks = 2 waves/SIMD. Wave w owns units
// {2w, 2w+1} of BOTH layers.
//
// mfma_f32_16x16x32_f16 fragments (K=16 mapping's natural extension):
//   A[m][k]: lane = m + 16*(k/8), reg j = k%8   (m = lane&15)
//   B[k][n]: lane = n + 16*(k/8), reg j = k%8
//   D[m][n]: lane = n + 16*(m/4), reg r = m%4   (verified family layout)
// K packing: k<16 = h1 index, k>=16 = h2 index. A tile-row m (permuted):
//   m>>2 in {0,1}: L1 gates (m&3) of unit 2w+(m>>2):  [Whh0 | 0]
//   m>>2 in {2,3}: L2 gates (m&3) of unit 2w+(m>>2)-2: [Wih1 | Whh1]
// So ONE MFMA yields, per lane (n, Lq): the 4 gates of (layer Lq>=2,
// unit u2 = 2w+(Lq&1)) for seq n -> lane-local LSTM update (R10-verified),
// tanh gate = compile-time reg 2.
//
// Slot colocation: at iter t, L1 lanes write h1[t], L2 lanes write h2[t-1]
// into the SAME row hx[t&1][n][.]; post-barrier each lane reads ONE b128 =
// its B-slice of [h1[t], h2[t-1]] — exactly what iter t+1 needs (L1 step
// t+1: h1[t]; L2 step t: h1[t], h2[t-1]). Slot reuse at t+2 is ordered by
// the t+1 barrier. Iter 0's fake L2 step (-1) is masked to h2[-1]=0, c2=0.
__global__ void __launch_bounds__(512, 1) lstm2_k32_kernel(
    const float* __restrict__ x,
    const float* __restrict__ Wih0, const float* __restrict__ Whh0,
    const float* __restrict__ bih0, const float* __restrict__ bhh0,
    const float* __restrict__ Wih1, const float* __restrict__ Whh1,
    const float* __restrict__ bih1, const float* __restrict__ bhh1,
    const float* __restrict__ Wout, const float* __restrict__ bout,
    float* __restrict__ out)
{
    const int tid  = threadIdx.x;
    const int w    = tid >> 6;         // wave 0..7: units {2w,2w+1}, both layers
    const int l    = tid & 63;
    const int n    = l & 15;           // seq col (B/D); A tile-row
    const int Lq   = l >> 4;           // k-octet / D row-quad
    const int isL2 = Lq >> 1;          // 0: L1-role lanes, 1: L2-role lanes
    const int u2   = 2 * w + (Lq & 1); // owned unit
    const int seq  = blockIdx.x * 16 + n;

    // x tile, f16 (dword stride 514 -> conflict-free b64 reads).
    __shared__ __align__(16) f16   x_lds[16][1028];
    // h exchange: [slot][seq][36 f16]: 0-15 h1 units, 16-31 h2, 32-35 pad.
    __shared__ __align__(16) f16   hx[2][16][36];
    __shared__ __align__(16) float h2fin[16][20];

    // ---- stage x (f32 global -> f16 LDS), coalesced, once.
    {
        const float* xblk = x + (size_t)blockIdx.x * 16 * T_LEN;
#pragma unroll
        for (int jj = 0; jj < 8; ++jj) {
            const int flat = jj * 2048 + tid * 4;      // f32 quad index
            const int row  = flat >> 10, col = flat & 1023;
            const float4 v = *reinterpret_cast<const float4*>(
                xblk + (size_t)row * T_LEN + col);
            f16x4 h4; h4[0] = (f16)v.x; h4[1] = (f16)v.y;
                      h4[2] = (f16)v.z; h4[3] = (f16)v.w;
            *reinterpret_cast<f16x4*>(&x_lds[row][col]) = h4;
        }
    }

    const float L2E = 1.442695041f;
    const float NT  = -2.f * L2E;      // tanh(c) scale

    // ---- A-fragment (8 f16): tile-row m = n, k = 8*Lq + j. Pre-scaled by
    //      the row-gate's -log2e (tanh rows x2).
    const int   mh  = n >> 2, mg = n & 3;
    const float nsm = (mg == 2) ? (-2.f * L2E) : (-L2E);
    f16x8 WA;
#pragma unroll
    for (int j = 0; j < 8; ++j) {
        const int k = 8 * Lq + j;
        float wv;
        if (mh < 2) {                  // L1 rows: [Whh0 | 0]
            const int wr = mg * 16 + 2 * w + mh;
            wv = (k < 16) ? Whh0[wr * 16 + k] : 0.f;
        } else {                       // L2 rows: [Wih1 | Whh1]
            const int wr = mg * 16 + 2 * w + (mh - 2);
            wv = (k < 16) ? Wih1[wr * 16 + k] : Whh1[wr * 16 + (k - 16)];
        }
        WA[j] = (f16)(nsm * wv);
    }
    // ---- D-side constants: acc reg r = gate r of (layer isL2, unit u2).
    f32x4 cbD, wxD;
#pragma unroll
    for (int r = 0; r < 4; ++r) {
        const float nsD = (r == 2) ? (-2.f * L2E) : (-L2E);
        const int   row = r * 16 + u2;
        if (!isL2) {
            cbD[r] = nsD * (bih0[row] + bhh0[row]);
            wxD[r] = nsD * Wih0[row];
        } else {
            cbD[r] = nsD * (bih1[row] + bhh1[row]);
            wxD[r] = 0.f;              // uniform ci code; no x term for L2
        }
    }
    asm volatile("" : "+v"(WA), "+v"(cbD), "+v"(wxD));

    f16x8 rh = {};                     // B-slice: [h1[t-1] | h2[t-2]] octet
    float cc = 0.f;                    // c1 (L1 lanes) / c2 (L2 lanes)

    __syncthreads();                   // x staged; orders weight loads

    f16x4 xq = *reinterpret_cast<const f16x4*>(&x_lds[n][0]);

    for (int tb = 0; tb < T_LEN; tb += 4) {
        f16x4 xn = xq;
        if (tb + 4 < T_LEN)
            xn = *reinterpret_cast<const f16x4*>(&x_lds[n][tb + 4]);
#pragma unroll
        for (int u = 0; u < 4; ++u) {
            const int t    = tb + u;
            const int slot = u & 1;            // == t&1

            // ---- the step: 1 MFMA + lane-local update.
            const float xv = (float)xq[u];
            f32x4 ci;
#pragma unroll
            for (int r = 0; r < 4; ++r)
                ci[r] = fmaf(wxD[r], xv, cbD[r]);
            const f32x4 d = mfma_k32(WA, rh, ci);
            const float si = sig2(d[0]);
            const float sf = sig2(d[1]);
            const float sg = fmaf(2.f, sig2(d[2]), -1.f);
            const float so = sig2(d[3]);
            float ccn = fmaf(sf, cc, si * sg);
            const float th = fmaf(2.f, sig2(NT * ccn), -1.f);
            float hv = so * th;
            if (t == 0 && isL2) { ccn = 0.f; hv = 0.f; }   // mask step -1
            cc = ccn;
            hx[slot][n][isL2 * 16 + u2] = (f16)hv;
            __syncthreads();
            // post-barrier b128: [h1[t] | h2[t-1]] slice for next iter.
            rh = *reinterpret_cast<const f16x8*>(&hx[slot][n][8 * Lq]);
        }
        xq = xn;
    }

    // ---- epilogue: L2 step 1023 from rh = [h1[1023] | h2[1022]].
    {
        const f32x4 d = mfma_k32(WA, rh, cbD);
        const float si = sig2(d[0]);
        const float sf = sig2(d[1]);
        const float sg = fmaf(2.f, sig2(d[2]), -1.f);
        const float so = sig2(d[3]);
        const float c2f = fmaf(sf, cc, si * sg);
        const float th  = fmaf(2.f, sig2(NT * c2f), -1.f);
        if (isL2) h2fin[n][u2] = so * th;      // f32 for the head
    }
    __syncthreads();

    // ---- head (wave 0): out[seq][m] = relu(h2) . Wout[m] + bout[m]
    if (w == 0) {
        const f32x4 hv4 = *reinterpret_cast<const f32x4*>(&h2fin[n][4 * Lq]);
#pragma unroll
        for (int m5 = 0; m5 < 5; ++m5) {
            float p = 0.f;
#pragma unroll
            for (int r = 0; r < 4; ++r)
                p = fmaf(fmaxf(hv4[r], 0.f), Wout[m5 * 16 + 4 * Lq + r], p);
            p += __shfl_xor(p, 16, 64);
            p += __shfl_xor(p, 32, 64);
            if (Lq == 0) out[seq * 5 + m5] = p + bout[m5];
        }
    }
}

extern "C" void kernel_launch(void* const* d_in, const int* in_sizes, int n_in,
                              void* d_out, int out_size, void* d_ws, size_t ws_size,
                              hipStream_t stream) {
    const float* x    = (const float*)d_in[0];
    const float* Wih0 = (const float*)d_in[1];
    const float* Whh0 = (const float*)d_in[2];
    const float* bih0 = (const float*)d_in[3];
    const float* bhh0 = (const float*)d_in[4];
    const float* Wih1 = (const float*)d_in[5];
    const float* Whh1 = (const float*)d_in[6];
    const float* bih1 = (const float*)d_in[7];
    const float* bhh1 = (const float*)d_in[8];
    const float* Wout = (const float*)d_in[9];
    const float* bout = (const float*)d_in[10];
    float* out = (float*)d_out;

    const int B = in_sizes[0] / T_LEN;          // 4096
    dim3 grid(B / 16), block(512);              // 8 uniform waves / 16 seqs
    hipLaunchKernelGGL(lstm2_k32_kernel, grid, block, 0, stream,
                       x, Wih0, Whh0, bih0, bhh0,
                       Wih1, Whh1, bih1, bhh1, Wout, bout, out);
}

// Round 18
// 240.095 us; speedup vs baseline: 1.5593x; 1.0132x over previous
//
#include <hip/hip_runtime.h>

static constexpr int T_LEN = 1024;

typedef _Float16 f16;
typedef f16  f16x4 __attribute__((ext_vector_type(4)));
typedef f16  f16x8 __attribute__((ext_vector_type(8)));
typedef float f32x4 __attribute__((ext_vector_type(4)));

__device__ __forceinline__ f32x4 mfma_k32(f16x8 a, f16x8 b, f32x4 c) {
    return __builtin_amdgcn_mfma_f32_16x16x32_f16(a, b, c, 0, 0, 0);
}
// 1/(1+2^t): overflow-safe (t->+inf: exp2=inf, rcp->0; t->-inf: ->1)
__device__ __forceinline__ float sig2(float t) {
    return __builtin_amdgcn_rcpf(1.f + __builtin_amdgcn_exp2f(t));
}

// Round-18: R17 (K32 one-MFMA-per-step, best 243 µs) + issue shave:
//  - t=0 peeled (no per-step mask)
//  - ping-pong LDS pointers precomputed (no per-step addressing)
//  - ci (bias + Wih0*x) hoisted per 4-step window (post-barrier window
//    contains only ds_read -> MFMA)
//  - x stored f32 in LDS (no per-step cvt), stride 1028 conflict-free
//  - hx rows padded to 40 f16 (80B) -> aligned b128 octet reads
// Arithmetic bit-identical to R17.
__global__ void __launch_bounds__(512, 1) lstm2_k32b_kernel(
    const float* __restrict__ x,
    const float* __restrict__ Wih0, const float* __restrict__ Whh0,
    const float* __restrict__ bih0, const float* __restrict__ bhh0,
    const float* __restrict__ Wih1, const float* __restrict__ Whh1,
    const float* __restrict__ bih1, const float* __restrict__ bhh1,
    const float* __restrict__ Wout, const float* __restrict__ bout,
    float* __restrict__ out)
{
    const int tid  = threadIdx.x;
    const int w    = tid >> 6;         // wave 0..7: units {2w,2w+1}, both layers
    const int l    = tid & 63;
    const int n    = l & 15;           // seq col (B/D); A tile-row
    const int Lq   = l >> 4;           // k-octet / D row-quad
    const int isL2 = Lq >> 1;          // 0: L1-role lanes, 1: L2-role lanes
    const int u2   = 2 * w + (Lq & 1); // owned unit
    const int seq  = blockIdx.x * 16 + n;

    // x tile, f32: stride 1028 dwords -> b128 reads bank-spread (2-way max).
    __shared__ __align__(16) float x_lds[16][1028];
    // h exchange: [slot][seq][40 f16] = 80B rows (16B-aligned octets).
    __shared__ __align__(16) f16   hx[2][16][40];
    __shared__ __align__(16) float h2fin[16][20];

    // ---- stage x (f32 global -> f32 LDS), coalesced, once.
    {
        const float* xblk = x + (size_t)blockIdx.x * 16 * T_LEN;
#pragma unroll
        for (int jj = 0; jj < 8; ++jj) {
            const int flat = jj * 2048 + tid * 4;      // f32 quad index
            const int row  = flat >> 10, col = flat & 1023;
            const float4 v = *reinterpret_cast<const float4*>(
                xblk + (size_t)row * T_LEN + col);
            *reinterpret_cast<float4*>(&x_lds[row][col]) = v;
        }
    }

    const float L2E = 1.442695041f;
    const float NT  = -2.f * L2E;      // tanh(c) scale

    // ---- A-fragment (8 f16): tile-row m = n, k = 8*Lq + j (R17-verified).
    const int   mh  = n >> 2, mg = n & 3;
    const float nsm = (mg == 2) ? (-2.f * L2E) : (-L2E);
    f16x8 WA;
#pragma unroll
    for (int j = 0; j < 8; ++j) {
        const int k = 8 * Lq + j;
        float wv;
        if (mh < 2) {                  // L1 rows: [Whh0 | 0]
            const int wr = mg * 16 + 2 * w + mh;
            wv = (k < 16) ? Whh0[wr * 16 + k] : 0.f;
        } else {                       // L2 rows: [Wih1 | Whh1]
            const int wr = mg * 16 + 2 * w + (mh - 2);
            wv = (k < 16) ? Wih1[wr * 16 + k] : Whh1[wr * 16 + (k - 16)];
        }
        WA[j] = (f16)(nsm * wv);
    }
    // ---- D-side constants: acc reg r = gate r of (layer isL2, unit u2).
    f32x4 cbD, wxD;
#pragma unroll
    for (int r = 0; r < 4; ++r) {
        const float nsD = (r == 2) ? (-2.f * L2E) : (-L2E);
        const int   row = r * 16 + u2;
        if (!isL2) {
            cbD[r] = nsD * (bih0[row] + bhh0[row]);
            wxD[r] = nsD * Wih0[row];
        } else {
            cbD[r] = nsD * (bih1[row] + bhh1[row]);
            wxD[r] = 0.f;
        }
    }
    asm volatile("" : "+v"(WA), "+v"(cbD), "+v"(wxD));

    // ---- precomputed ping-pong exchange pointers.
    f16* const wp0 = &hx[0][n][isL2 * 16 + u2];
    f16* const wp1 = &hx[1][n][isL2 * 16 + u2];
    const f16x8* const rp0 = reinterpret_cast<const f16x8*>(&hx[0][n][8 * Lq]);
    const f16x8* const rp1 = reinterpret_cast<const f16x8*>(&hx[1][n][8 * Lq]);

    f16x8 rh = {};                     // B-slice: [h1[t-1] | h2[t-2]] octet
    float cc = 0.f;                    // c1 (L1 lanes) / c2 (L2 lanes)

    __syncthreads();                   // x staged; orders weight loads

// one step: MFMA + lane-local update + exchange. MASK0 is compile-time.
#define LSTM_STEP(UIDX, CIV, MASK0)                                   \
    {                                                                 \
        const f32x4 d = mfma_k32(WA, rh, (CIV));                      \
        const float si = sig2(d[0]);                                  \
        const float sf = sig2(d[1]);                                  \
        const float sg = fmaf(2.f, sig2(d[2]), -1.f);                 \
        const float so = sig2(d[3]);                                  \
        float ccn = fmaf(sf, cc, si * sg);                            \
        const float th = fmaf(2.f, sig2(NT * ccn), -1.f);             \
        float hv = so * th;                                           \
        if (MASK0 && isL2) { ccn = 0.f; hv = 0.f; }                   \
        cc = ccn;                                                     \
        *(((UIDX) & 1) ? wp1 : wp0) = (f16)hv;                        \
        __syncthreads();                                              \
        rh = *(((UIDX) & 1) ? rp1 : rp0);                             \
    }

    // ---- first window (t = 0..3): mask fake L2 step -1 at t=0.
    float4 xw = *reinterpret_cast<const float4*>(&x_lds[n][0]);
    float4 xnx = *reinterpret_cast<const float4*>(&x_lds[n][4]);
    {
        f32x4 ci0, ci1, ci2, ci3;
#pragma unroll
        for (int r = 0; r < 4; ++r) {
            ci0[r] = fmaf(wxD[r], xw.x, cbD[r]);
            ci1[r] = fmaf(wxD[r], xw.y, cbD[r]);
            ci2[r] = fmaf(wxD[r], xw.z, cbD[r]);
            ci3[r] = fmaf(wxD[r], xw.w, cbD[r]);
        }
        LSTM_STEP(0, ci0, true)
        LSTM_STEP(1, ci1, false)
        LSTM_STEP(2, ci2, false)
        LSTM_STEP(3, ci3, false)
    }
    xw = xnx;

    // ---- steady loop (t = 4..1023), no masks, pointers precomputed.
    for (int tb = 4; tb < T_LEN; tb += 4) {
        float4 xn2 = xw;
        if (tb + 4 < T_LEN)
            xn2 = *reinterpret_cast<const float4*>(&x_lds[n][tb + 4]);
        f32x4 ci0, ci1, ci2, ci3;
#pragma unroll
        for (int r = 0; r < 4; ++r) {
            ci0[r] = fmaf(wxD[r], xw.x, cbD[r]);
            ci1[r] = fmaf(wxD[r], xw.y, cbD[r]);
            ci2[r] = fmaf(wxD[r], xw.z, cbD[r]);
            ci3[r] = fmaf(wxD[r], xw.w, cbD[r]);
        }
        LSTM_STEP(0, ci0, false)
        LSTM_STEP(1, ci1, false)
        LSTM_STEP(2, ci2, false)
        LSTM_STEP(3, ci3, false)
        xw = xn2;
    }
#undef LSTM_STEP

    // ---- epilogue: L2 step 1023 from rh = [h1[1023] | h2[1022]].
    {
        const f32x4 d = mfma_k32(WA, rh, cbD);
        const float si = sig2(d[0]);
        const float sf = sig2(d[1]);
        const float sg = fmaf(2.f, sig2(d[2]), -1.f);
        const float so = sig2(d[3]);
        const float c2f = fmaf(sf, cc, si * sg);
        const float th  = fmaf(2.f, sig2(NT * c2f), -1.f);
        if (isL2) h2fin[n][u2] = so * th;      // f32 for the head
    }
    __syncthreads();

    // ---- head (wave 0): out[seq][m] = relu(h2) . Wout[m] + bout[m]
    if (w == 0) {
        const f32x4 hv4 = *reinterpret_cast<const f32x4*>(&h2fin[n][4 * Lq]);
#pragma unroll
        for (int m5 = 0; m5 < 5; ++m5) {
            float p = 0.f;
#pragma unroll
            for (int r = 0; r < 4; ++r)
                p = fmaf(fmaxf(hv4[r], 0.f), Wout[m5 * 16 + 4 * Lq + r], p);
            p += __shfl_xor(p, 16, 64);
            p += __shfl_xor(p, 32, 64);
            if (Lq == 0) out[seq * 5 + m5] = p + bout[m5];
        }
    }
}

extern "C" void kernel_launch(void* const* d_in, const int* in_sizes, int n_in,
                              void* d_out, int out_size, void* d_ws, size_t ws_size,
                              hipStream_t stream) {
    const float* x    = (const float*)d_in[0];
    const float* Wih0 = (const float*)d_in[1];
    const float* Whh0 = (const float*)d_in[2];
    const float* bih0 = (const float*)d_in[3];
    const float* bhh0 = (const float*)d_in[4];
    const float* Wih1 = (const float*)d_in[5];
    const float* Whh1 = (const float*)d_in[6];
    const float* bih1 = (const float*)d_in[7];
    const float* bhh1 = (const float*)d_in[8];
    const float* Wout = (const float*)d_in[9];
    const float* bout = (const float*)d_in[10];
    float* out = (float*)d_out;

    const int B = in_sizes[0] / T_LEN;          // 4096
    dim3 grid(B / 16), block(512);              // 8 uniform waves / 16 seqs
    hipLaunchKernelGGL(lstm2_k32b_kernel, grid, block, 0, stream,
                       x, Wih0, Whh0, bih0, bhh0,
                       Wih1, Whh1, bih1, bhh1, Wout, bout, out);
}